// Round 3
// baseline (12218.460 us; speedup 1.0000x reference)
//
#include <hip/hip_runtime.h>
#include <hip/hip_bf16.h>

// ---------------------------------------------------------------------------
// StyleEncoder fused fp32 pipeline for MI355X (gfx950).
// All inputs fp32 (per reference); d_out fp32:
//   out[16*256*512] @0, vq_loss @2097152, idx (as float) @2097153.
// B=16, T=2048, L=512, H=256, 2H=512, KS=3, CVQ=64, K=128, NL*NB=10.
// ---------------------------------------------------------------------------

#define OUT_LOSS_OFF 2097152
#define OUT_IDX_OFF  2097153

// ---------------- weight transposes ----------------------------------------
// w [G][O][Cin][3] -> wt [G][Cin*3][O]
__global__ __launch_bounds__(256) void k_t_conv3(const float* __restrict__ w,
                                                 float* __restrict__ wt,
                                                 int G, int O, int Cin) {
    size_t n = (size_t)G * O * Cin * 3;
    for (size_t i = (size_t)blockIdx.x * 256 + threadIdx.x; i < n;
         i += (size_t)gridDim.x * 256) {
        int k = (int)(i % 3);
        size_t r = i / 3;
        int c = (int)(r % Cin); r /= Cin;
        int o = (int)(r % O);
        int g = (int)(r / O);
        wt[((size_t)g * Cin * 3 + (size_t)(c * 3 + k)) * O + o] = w[i];
    }
}

// w [G][O][I] -> wt [G][I][O]
__global__ __launch_bounds__(256) void k_t_mat(const float* __restrict__ w,
                                               float* __restrict__ wt,
                                               int G, int O, int I) {
    size_t n = (size_t)G * O * I;
    for (size_t i = (size_t)blockIdx.x * 256 + threadIdx.x; i < n;
         i += (size_t)gridDim.x * 256) {
        int ci = (int)(i % I);
        int o  = (int)((i / I) % O);
        int g  = (int)(i / ((size_t)I * O));
        wt[((size_t)g * I + ci) * O + o] = w[i];
    }
}

// ---------------- pointwise conv (GEMM over channels) -----------------------
// y[b,o,t] = sum_i wt[i][o]*x[b,i,t] + bias[o]  (optional *mask[b,t])
template <int CIN, int COUT, int CHUNK>
__global__ __launch_bounds__(256) void k_pw(const float* __restrict__ x,
                                            const float* __restrict__ wt,
                                            const float* __restrict__ bias,
                                            const float* __restrict__ mask,
                                            float* __restrict__ y, int T) {
    extern __shared__ float X[];  // [CIN][64]
    const int b = blockIdx.y, t0 = blockIdx.x * 64;
    for (int i = threadIdx.x; i < CIN * 64; i += 256) {
        int ci = i >> 6, j = i & 63;
        X[i] = x[((size_t)b * CIN + ci) * T + t0 + j];
    }
    __syncthreads();
    const int tl = threadIdx.x & 63;
    const int g = __builtin_amdgcn_readfirstlane((int)(threadIdx.x >> 6));
    float acc[CHUNK];
#pragma unroll
    for (int o = 0; o < CHUNK; o++) acc[o] = 0.f;
    for (int i = 0; i < CIN; i++) {
        float xv = X[i * 64 + tl];
        const float* wr = wt + (size_t)i * COUT + g * CHUNK;  // wave-uniform -> s_load
#pragma unroll
        for (int o = 0; o < CHUNK; o++) acc[o] = fmaf(wr[o], xv, acc[o]);
    }
    float mk = mask ? mask[(size_t)b * T + t0 + tl] : 1.0f;
#pragma unroll
    for (int o = 0; o < CHUNK; o++) {
        int oc = g * CHUNK + o;
        y[((size_t)b * COUT + oc) * T + t0 + tl] = (acc[o] + bias[oc]) * mk;
    }
}

// ---------------- fused residual sub-block ----------------------------------
// x_out = (x_in + W2( gelu( (W1*LN(x_in) + b1) * 3^-0.5 ) ) + b2) * mask
// w1t: [768][512] (row = c*3+k), w2t: [512][256]
__global__ __launch_bounds__(512) void k_subblock(
    const float* __restrict__ xin, float* __restrict__ xout,
    const float* __restrict__ lng, const float* __restrict__ lnb,
    const float* __restrict__ w1t, const float* __restrict__ b1,
    const float* __restrict__ w2t, const float* __restrict__ b2,
    const float* __restrict__ mask, int T) {
    extern __shared__ float sm[];
    float* BT   = sm;                 // 256*66 (cols t0-2..t0+63)
    float* CT   = sm + 256 * 66;      // 256*64
    float* red  = CT + 256 * 64;      // 66*8
    float* red2 = red + 528;          // 66*8
    float* mm   = red2 + 528;         // 66
    float* iv   = mm + 66;            // 66

    const int b = blockIdx.y;
    const int t0 = blockIdx.x * 64;
    const size_t xoff = (size_t)b * 256 * T;

    for (int i = threadIdx.x; i < 256 * 66; i += 512) {
        int c = i / 66, j = i - c * 66;
        int t = t0 - 2 + j;
        BT[i] = (t >= 0) ? xin[xoff + (size_t)c * T + t] : 0.0f;
    }
    __syncthreads();
    for (int i = threadIdx.x; i < 528; i += 512) {  // 66 cols x 8 segs
        int col = i % 66, seg = i / 66;
        float s = 0.f, s2 = 0.f;
        int c0 = seg * 32;
        for (int c = c0; c < c0 + 32; ++c) {
            float v = BT[c * 66 + col];
            s += v; s2 += v * v;
        }
        red[col * 8 + seg] = s; red2[col * 8 + seg] = s2;
    }
    __syncthreads();
    if (threadIdx.x < 66) {
        int col = threadIdx.x;
        float s = 0.f, s2 = 0.f;
        for (int k = 0; k < 8; k++) { s += red[col * 8 + k]; s2 += red2[col * 8 + k]; }
        float m = s * (1.0f / 256.0f);
        float v = s2 * (1.0f / 256.0f) - m * m;
        mm[col] = m;
        iv[col] = 1.0f / sqrtf(v + 1e-5f);
    }
    __syncthreads();
    for (int i = threadIdx.x; i < 256 * 66; i += 512) {
        int c = i / 66, j = i - c * 66;
        int t = t0 - 2 + j;
        float val = 0.f;
        if (t >= 0) val = (BT[i] - mm[j]) * iv[j] * lng[c] + lnb[c];
        BT[i] = val;  // causal zero-pad for t<0
    }

    const int tl = threadIdx.x & 63;
    const int g = __builtin_amdgcn_readfirstlane((int)(threadIdx.x >> 6));
    float acc2[32];
#pragma unroll
    for (int o = 0; o < 32; o++) acc2[o] = 0.f;
    const float kscale = 0.5773502691896258f;  // 3^-0.5

    for (int p = 0; p < 2; ++p) {
        __syncthreads();  // BT ready (p=0) / CT consumed (p=1)
        float acc[32];
#pragma unroll
        for (int o = 0; o < 32; o++) acc[o] = 0.f;
        const float* w1p = w1t + (p * 256 + g * 32);  // wave-uniform offset
        for (int c = 0; c < 256; ++c) {
#pragma unroll
            for (int k = 0; k < 3; ++k) {
                float xv = BT[c * 66 + tl + k];
                const float* wr = w1p + (size_t)(c * 3 + k) * 512;
#pragma unroll
                for (int o = 0; o < 32; o++) acc[o] = fmaf(wr[o], xv, acc[o]);
            }
        }
#pragma unroll
        for (int o = 0; o < 32; o++) {
            int oc = p * 256 + g * 32 + o;
            float y = (acc[o] + b1[oc]) * kscale;
            float ge = 0.5f * y * (1.0f + erff(y * 0.7071067811865476f));
            CT[(g * 32 + o) * 64 + tl] = ge;
        }
        __syncthreads();
        const float* w2p = w2t + (size_t)p * 256 * 256 + g * 32;
        for (int i2 = 0; i2 < 256; ++i2) {
            float xv = CT[i2 * 64 + tl];
            const float* wr = w2p + (size_t)i2 * 256;
#pragma unroll
            for (int o = 0; o < 32; o++) acc2[o] = fmaf(wr[o], xv, acc2[o]);
        }
    }
    float mk = mask[(size_t)b * T + t0 + tl];
#pragma unroll
    for (int o = 0; o < 32; o++) {
        int oc = g * 32 + o;
        size_t adr = xoff + (size_t)oc * T + t0 + tl;
        xout[adr] = (xin[adr] + acc2[o] + b2[oc]) * mk;
    }
}

// ---------------- final LN + causal conv (k=3, 256->256) --------------------
__global__ __launch_bounds__(512) void k_lnconv(
    const float* __restrict__ xin, float* __restrict__ xout,
    const float* __restrict__ lg, const float* __restrict__ lb,
    const float* __restrict__ wt, const float* __restrict__ bias,
    const float* __restrict__ mask, int T) {
    extern __shared__ float sm[];
    float* BT = sm;             // 256*66
    float* red = sm + 256 * 66; // 528
    float* red2 = red + 528;    // 528
    float* mm = red2 + 528;     // 66
    float* iv = mm + 66;        // 66

    const int b = blockIdx.y;
    const int t0 = blockIdx.x * 64;
    const size_t xoff = (size_t)b * 256 * T;

    for (int i = threadIdx.x; i < 256 * 66; i += 512) {
        int c = i / 66, j = i - c * 66;
        int t = t0 - 2 + j;
        BT[i] = (t >= 0) ? xin[xoff + (size_t)c * T + t] : 0.0f;
    }
    __syncthreads();
    for (int i = threadIdx.x; i < 528; i += 512) {
        int col = i % 66, seg = i / 66;
        float s = 0.f, s2 = 0.f;
        int c0 = seg * 32;
        for (int c = c0; c < c0 + 32; ++c) {
            float v = BT[c * 66 + col];
            s += v; s2 += v * v;
        }
        red[col * 8 + seg] = s; red2[col * 8 + seg] = s2;
    }
    __syncthreads();
    if (threadIdx.x < 66) {
        int col = threadIdx.x;
        float s = 0.f, s2 = 0.f;
        for (int k = 0; k < 8; k++) { s += red[col * 8 + k]; s2 += red2[col * 8 + k]; }
        float m = s * (1.0f / 256.0f);
        float v = s2 * (1.0f / 256.0f) - m * m;
        mm[col] = m;
        iv[col] = 1.0f / sqrtf(v + 1e-5f);
    }
    __syncthreads();
    for (int i = threadIdx.x; i < 256 * 66; i += 512) {
        int c = i / 66, j = i - c * 66;
        int t = t0 - 2 + j;
        float val = 0.f;
        if (t >= 0)
            val = ((BT[i] - mm[j]) * iv[j] * lg[c] + lb[c]) * mask[(size_t)b * T + t];
        BT[i] = val;
    }
    __syncthreads();
    const int tl = threadIdx.x & 63;
    const int g = __builtin_amdgcn_readfirstlane((int)(threadIdx.x >> 6));
    float acc[32];
#pragma unroll
    for (int o = 0; o < 32; o++) acc[o] = 0.f;
    const float* wp = wt + g * 32;
    for (int c = 0; c < 256; ++c) {
#pragma unroll
        for (int k = 0; k < 3; ++k) {
            float xv = BT[c * 66 + tl + k];
            const float* wr = wp + (size_t)(c * 3 + k) * 256;
#pragma unroll
            for (int o = 0; o < 32; o++) acc[o] = fmaf(wr[o], xv, acc[o]);
        }
    }
    float mk = mask[(size_t)b * T + t0 + tl];
#pragma unroll
    for (int o = 0; o < 32; o++) {
        int oc = g * 32 + o;
        xout[xoff + (size_t)oc * T + t0 + tl] = (acc[o] + bias[oc]) * mk;
    }
}

// ---------------- group-by-segments (scatter mean) --------------------------
__global__ __launch_bounds__(256) void k_counts(const int* __restrict__ m2p,
                                                int* __restrict__ cnt) {
    __shared__ int c[512];
    int b = blockIdx.x;
    for (int i = threadIdx.x; i < 512; i += 256) c[i] = 0;
    __syncthreads();
    for (int t = threadIdx.x; t < 2048; t += 256) {
        int p = m2p[b * 2048 + t];
        if (p >= 1 && p <= 512) atomicAdd(&c[p - 1], 1);
    }
    __syncthreads();
    for (int i = threadIdx.x; i < 512; i += 256) cnt[b * 512 + i] = c[i];
}

__global__ __launch_bounds__(256) void k_scatter(const float* __restrict__ h,
                                                 const int* __restrict__ m2p,
                                                 float* __restrict__ g) {
    extern __shared__ float sm[];
    float* HT = sm;                    // 256*65 (padded)
    int* ph = (int*)(sm + 256 * 65);   // 64
    int b = blockIdx.y, t0 = blockIdx.x * 64;
    if (threadIdx.x < 64) ph[threadIdx.x] = m2p[b * 2048 + t0 + threadIdx.x];
    for (int i = threadIdx.x; i < 256 * 64; i += 256) {
        int c = i >> 6, j = i & 63;
        HT[c * 65 + j] = h[((size_t)b * 256 + c) * 2048 + t0 + j];
    }
    __syncthreads();
    int c = threadIdx.x;
    float run = 0.f;
    int cur = ph[0];
    for (int j = 0; j < 64; j++) {
        int p = ph[j];
        if (p != cur) {
            if (cur >= 1 && cur <= 512)
                atomicAdd(&g[((size_t)b * 256 + c) * 512 + cur - 1], run);
            run = 0.f;
            cur = p;
        }
        run += HT[c * 65 + j];
    }
    if (cur >= 1 && cur <= 512)
        atomicAdd(&g[((size_t)b * 256 + c) * 512 + cur - 1], run);
}

__global__ __launch_bounds__(256) void k_divide(float* __restrict__ g,
                                                const int* __restrict__ cnt) {
    int n = blockIdx.x * 256 + threadIdx.x;
    if (n >= 16 * 256 * 512) return;
    int l = n & 511;
    int b = n >> 17;  // 256*512 = 2^17
    int c1 = cnt[b * 512 + l];
    if (c1 < 1) c1 = 1;
    g[n] = g[n] / (float)c1;
}

// ---------------- VQ --------------------------------------------------------
__global__ __launch_bounds__(256) void k_vq(const float* __restrict__ z,
                                            const float* __restrict__ cb,
                                            int* __restrict__ idxout,
                                            float* __restrict__ out,
                                            float* __restrict__ lossacc) {
    int n = blockIdx.x * 256 + threadIdx.x;  // 0..8191
    int b = n >> 9, l = n & 511;
    float zr[64];
#pragma unroll
    for (int c = 0; c < 64; c++) zr[c] = z[((size_t)b * 64 + c) * 512 + l];
    float best = 3.4e38f;
    int bi = 0;
    for (int k = 0; k < 128; k++) {
        const float* cr = cb + k * 64;  // uniform -> s_load
        float d = 0.f;
#pragma unroll
        for (int c = 0; c < 64; c++) {
            float t = zr[c] - cr[c];
            d = fmaf(t, t, d);
        }
        if (d < best) { best = d; bi = k; }  // strict < == np first-argmin
    }
    idxout[n] = bi;
    out[OUT_IDX_OFF + n] = (float)bi;
    atomicAdd(lossacc, best);  // sum of ||z-q||^2 == loss numerator
}

__global__ void k_loss(const float* __restrict__ acc,
                       float* __restrict__ out) {
    if (threadIdx.x == 0 && blockIdx.x == 0)
        out[OUT_LOSS_OFF] = 0.25f * acc[0] * (1.0f / 524288.0f);
}

// ---------------- proj_out (q = codebook[idx]) ------------------------------
__global__ __launch_bounds__(256) void k_projout(const float* __restrict__ cb,
                                                 const int* __restrict__ idx,
                                                 const float* __restrict__ wt,  // [64][256]
                                                 const float* __restrict__ bias,
                                                 float* __restrict__ out) {
    __shared__ float Q[64 * 64];  // [c][l]
    __shared__ int ids[64];
    int b = blockIdx.y, l0 = blockIdx.x * 64;
    if (threadIdx.x < 64) ids[threadIdx.x] = idx[b * 512 + l0 + threadIdx.x];
    __syncthreads();
    for (int i = threadIdx.x; i < 4096; i += 256) {
        int c = i >> 6, l = i & 63;
        Q[c * 64 + l] = cb[ids[l] * 64 + c];
    }
    __syncthreads();
    int tl = threadIdx.x & 63;
    int g = __builtin_amdgcn_readfirstlane((int)(threadIdx.x >> 6));
    float acc[64];
#pragma unroll
    for (int o = 0; o < 64; o++) acc[o] = 0.f;
    for (int i = 0; i < 64; i++) {
        float xv = Q[i * 64 + tl];
        const float* wr = wt + i * 256 + g * 64;
#pragma unroll
        for (int o = 0; o < 64; o++) acc[o] = fmaf(wr[o], xv, acc[o]);
    }
#pragma unroll
    for (int o = 0; o < 64; o++) {
        int oc = g * 64 + o;
        out[(size_t)b * 131072 + (size_t)oc * 512 + l0 + tl] = acc[o] + bias[oc];
    }
}

// ---------------------------------------------------------------------------
extern "C" void kernel_launch(void* const* d_in, const int* in_sizes, int n_in,
                              void* d_out, int out_size, void* d_ws, size_t ws_size,
                              hipStream_t stream) {
    (void)in_sizes; (void)n_in; (void)out_size; (void)ws_size;
    const float* x          = (const float*)d_in[0];
    const float* in_np      = (const float*)d_in[1];
    const int*   mel2ph     = (const int*)d_in[2];
    const float* ph_np      = (const float*)d_in[3];
    const float* conv_in_w  = (const float*)d_in[4];
    const float* conv_in_b  = (const float*)d_in[5];
    const float* e_ln_g = (const float*)d_in[6];
    const float* e_ln_b = (const float*)d_in[7];
    const float* e_w1   = (const float*)d_in[8];
    const float* e_b1   = (const float*)d_in[9];
    const float* e_w2   = (const float*)d_in[10];
    const float* e_b2   = (const float*)d_in[11];
    const float* e_lg   = (const float*)d_in[12];
    const float* e_lb   = (const float*)d_in[13];
    const float* e_pw   = (const float*)d_in[14];
    const float* e_pb   = (const float*)d_in[15];
    const float* p_ln_g = (const float*)d_in[16];
    const float* p_ln_b = (const float*)d_in[17];
    const float* p_w1   = (const float*)d_in[18];
    const float* p_b1   = (const float*)d_in[19];
    const float* p_w2   = (const float*)d_in[20];
    const float* p_b2   = (const float*)d_in[21];
    const float* p_lg   = (const float*)d_in[22];
    const float* p_lb   = (const float*)d_in[23];
    const float* p_pw   = (const float*)d_in[24];
    const float* p_pb   = (const float*)d_in[25];
    const float* proj_in_w  = (const float*)d_in[26];
    const float* proj_in_b  = (const float*)d_in[27];
    const float* proj_out_w = (const float*)d_in[28];
    const float* proj_out_b = (const float*)d_in[29];
    const float* codebook   = (const float*)d_in[30];
    float* out = (float*)d_out;

    float* ws = (float*)d_ws;
    float* A      = ws;                        // 16*256*2048 = 8388608
    float* Bb     = A + 8388608;               // 8388608
    float* W1T_E  = Bb + 8388608;              // 10*768*512 = 3932160
    float* W1T_P  = W1T_E + 3932160;
    float* W2T_E  = W1T_P + 3932160;           // 10*512*256 = 1310720
    float* W2T_P  = W2T_E + 1310720;
    float* CINT   = W2T_P + 1310720;           // 80*256
    float* PSTT_E = CINT + 20480;              // 768*256
    float* PSTT_P = PSTT_E + 196608;
    float* PINT   = PSTT_P + 196608;           // 256*64
    float* POUTT  = PINT + 16384;              // 64*256
    float* Z      = POUTT + 16384;             // 16*64*512 = 524288
    int*   CNT    = (int*)(Z + 524288);        // 8192
    int*   IDX    = CNT + 8192;                // 8192
    float* LOSS   = (float*)(IDX + 8192);      // 1

    // weight transposes (d_ws is re-poisoned every call -> recompute)
    k_t_conv3<<<dim3(2048), dim3(256), 0, stream>>>(e_w1, W1T_E, 10, 512, 256);
    k_t_conv3<<<dim3(2048), dim3(256), 0, stream>>>(p_w1, W1T_P, 10, 512, 256);
    k_t_mat  <<<dim3(1024), dim3(256), 0, stream>>>(e_w2, W2T_E, 10, 256, 512);
    k_t_mat  <<<dim3(1024), dim3(256), 0, stream>>>(p_w2, W2T_P, 10, 256, 512);
    k_t_mat  <<<dim3(80),   dim3(256), 0, stream>>>(conv_in_w, CINT, 1, 256, 80);
    k_t_conv3<<<dim3(768),  dim3(256), 0, stream>>>(e_pw, PSTT_E, 1, 256, 256);
    k_t_conv3<<<dim3(768),  dim3(256), 0, stream>>>(p_pw, PSTT_P, 1, 256, 256);
    k_t_mat  <<<dim3(64),   dim3(256), 0, stream>>>(proj_in_w, PINT, 1, 64, 256);
    k_t_mat  <<<dim3(64),   dim3(256), 0, stream>>>(proj_out_w, POUTT, 1, 256, 64);

    const size_t sm_sub = (256 * 66 + 256 * 64 + 528 + 528 + 66 + 66) * sizeof(float);
    const size_t sm_lnc = (256 * 66 + 528 + 528 + 66 + 66) * sizeof(float);
    const size_t sm_scat = 256 * 65 * sizeof(float) + 64 * sizeof(int);

    // ---- conv_in + mask -> A
    k_pw<80, 256, 64><<<dim3(32, 16), dim3(256), 80 * 64 * 4, stream>>>(
        x, CINT, conv_in_b, in_np, A, 2048);

    // ---- encoder: 10 sub-blocks, ping-pong A<->B (ends in A)
    float* cur = A;
    float* nxt = Bb;
    for (int s = 0; s < 10; s++) {
        k_subblock<<<dim3(32, 16), dim3(512), sm_sub, stream>>>(
            cur, nxt, e_ln_g + s * 256, e_ln_b + s * 256,
            W1T_E + (size_t)s * 768 * 512, e_b1 + s * 512,
            W2T_E + (size_t)s * 512 * 256, e_b2 + s * 256, in_np, 2048);
        float* t = cur; cur = nxt; nxt = t;
    }
    // ---- final LN + post conv: A -> B
    k_lnconv<<<dim3(32, 16), dim3(512), sm_lnc, stream>>>(
        cur, nxt, e_lg, e_lb, PSTT_E, e_pb, in_np, 2048);

    // ---- group-by-segs: B (T=2048) -> A (compact [16,256,512])
    hipMemsetAsync(A, 0, (size_t)2097152 * 4, stream);
    hipMemsetAsync(LOSS, 0, 4, stream);
    k_counts<<<dim3(16), dim3(256), 0, stream>>>(mel2ph, CNT);
    k_scatter<<<dim3(32, 16), dim3(256), sm_scat, stream>>>(Bb, mel2ph, A);
    k_divide<<<dim3(8192), dim3(256), 0, stream>>>(A, CNT);

    // ---- postnet: 10 sub-blocks on T=512, ping-pong (ends in A)
    cur = A; nxt = Bb;
    for (int s = 0; s < 10; s++) {
        k_subblock<<<dim3(8, 16), dim3(512), sm_sub, stream>>>(
            cur, nxt, p_ln_g + s * 256, p_ln_b + s * 256,
            W1T_P + (size_t)s * 768 * 512, p_b1 + s * 512,
            W2T_P + (size_t)s * 512 * 256, p_b2 + s * 256, ph_np, 512);
        float* t = cur; cur = nxt; nxt = t;
    }
    k_lnconv<<<dim3(8, 16), dim3(512), sm_lnc, stream>>>(
        cur, nxt, p_lg, p_lb, PSTT_P, p_pb, ph_np, 512);

    // ---- proj_in: B -> Z [16,64,512]
    k_pw<256, 64, 16><<<dim3(8, 16), dim3(256), 256 * 64 * 4, stream>>>(
        Bb, PINT, proj_in_b, nullptr, Z, 512);

    // ---- VQ + loss + proj_out
    k_vq<<<dim3(32), dim3(256), 0, stream>>>(Z, codebook, IDX, out, LOSS);
    k_loss<<<dim3(1), dim3(64), 0, stream>>>(LOSS, out);
    k_projout<<<dim3(8, 16), dim3(256), 0, stream>>>(codebook, IDX, POUTT,
                                                     proj_out_b, out);
}

// Round 4
// 10540.132 us; speedup vs baseline: 1.1592x; 1.1592x over previous
//
#include <hip/hip_runtime.h>
#include <hip/hip_bf16.h>

// ---------------------------------------------------------------------------
// StyleEncoder fused fp32 pipeline for MI355X (gfx950).
// All inputs fp32; d_out fp32:
//   out[16*256*512] @0, vq_loss @2097152, idx (as float) @2097153.
// B=16, T=2048, L=512, H=256, 2H=512, KS=3, CVQ=64, K=128, NL*NB=10.
// R4: split sub-block into k_conv1 (LN+conv+gelu -> global) + k_conv2
//     (1x1+residual). LDS per kernel <= 80 KB -> 2 blocks/CU (was 1).
// ---------------------------------------------------------------------------

#define OUT_LOSS_OFF 2097152
#define OUT_IDX_OFF  2097153

// ---------------- weight transposes ----------------------------------------
// w [G][O][Cin][3] -> wt [G][Cin*3][O]
__global__ __launch_bounds__(256) void k_t_conv3(const float* __restrict__ w,
                                                 float* __restrict__ wt,
                                                 int G, int O, int Cin) {
    size_t n = (size_t)G * O * Cin * 3;
    for (size_t i = (size_t)blockIdx.x * 256 + threadIdx.x; i < n;
         i += (size_t)gridDim.x * 256) {
        int k = (int)(i % 3);
        size_t r = i / 3;
        int c = (int)(r % Cin); r /= Cin;
        int o = (int)(r % O);
        int g = (int)(r / O);
        wt[((size_t)g * Cin * 3 + (size_t)(c * 3 + k)) * O + o] = w[i];
    }
}

// w [G][O][I] -> wt [G][I][O]
__global__ __launch_bounds__(256) void k_t_mat(const float* __restrict__ w,
                                               float* __restrict__ wt,
                                               int G, int O, int I) {
    size_t n = (size_t)G * O * I;
    for (size_t i = (size_t)blockIdx.x * 256 + threadIdx.x; i < n;
         i += (size_t)gridDim.x * 256) {
        int ci = (int)(i % I);
        int o  = (int)((i / I) % O);
        int g  = (int)(i / ((size_t)I * O));
        wt[((size_t)g * I + ci) * O + o] = w[i];
    }
}

// ---------------- pointwise conv (GEMM over channels) -----------------------
template <int CIN, int COUT, int CHUNK>
__global__ __launch_bounds__(256) void k_pw(const float* __restrict__ x,
                                            const float* __restrict__ wt,
                                            const float* __restrict__ bias,
                                            const float* __restrict__ mask,
                                            float* __restrict__ y, int T) {
    extern __shared__ float X[];  // [CIN][64]
    const int b = blockIdx.y, t0 = blockIdx.x * 64;
    for (int i = threadIdx.x; i < CIN * 64; i += 256) {
        int ci = i >> 6, j = i & 63;
        X[i] = x[((size_t)b * CIN + ci) * T + t0 + j];
    }
    __syncthreads();
    const int tl = threadIdx.x & 63;
    const int g = __builtin_amdgcn_readfirstlane((int)(threadIdx.x >> 6));
    float acc[CHUNK];
#pragma unroll
    for (int o = 0; o < CHUNK; o++) acc[o] = 0.f;
    for (int i = 0; i < CIN; i++) {
        float xv = X[i * 64 + tl];
        const float* wr = wt + (size_t)i * COUT + g * CHUNK;  // wave-uniform
#pragma unroll
        for (int o = 0; o < CHUNK; o++) acc[o] = fmaf(wr[o], xv, acc[o]);
    }
    float mk = mask ? mask[(size_t)b * T + t0 + tl] : 1.0f;
#pragma unroll
    for (int o = 0; o < CHUNK; o++) {
        int oc = g * CHUNK + o;
        y[((size_t)b * COUT + oc) * T + t0 + tl] = (acc[o] + bias[oc]) * mk;
    }
}

// ---------------- sub-block part 1: LN + causal conv(256->512) + GELU -------
// gout[b][oc][t] = gelu((W1*LN(x))[oc,t]*3^-0.5 + ...), oc in [0,512)
// LDS = 72 KB -> 2 blocks/CU.
__global__ __launch_bounds__(512, 4) void k_conv1(
    const float* __restrict__ xin, float* __restrict__ gout,
    const float* __restrict__ lng, const float* __restrict__ lnb,
    const float* __restrict__ w1t, const float* __restrict__ b1, int T) {
    extern __shared__ float sm[];
    float* BT   = sm;                 // 256*66 (cols t0-2..t0+63)
    float* red  = sm + 256 * 66;      // 66*8
    float* red2 = red + 528;          // 66*8
    float* mm   = red2 + 528;         // 66
    float* iv   = mm + 66;            // 66

    const int b = blockIdx.y;
    const int t0 = blockIdx.x * 64;
    const size_t xoff = (size_t)b * 256 * T;

    for (int i = threadIdx.x; i < 256 * 66; i += 512) {
        int c = i / 66, j = i - c * 66;
        int t = t0 - 2 + j;
        BT[i] = (t >= 0) ? xin[xoff + (size_t)c * T + t] : 0.0f;
    }
    __syncthreads();
    for (int i = threadIdx.x; i < 528; i += 512) {  // 66 cols x 8 segs
        int col = i % 66, seg = i / 66;
        float s = 0.f, s2 = 0.f;
        int c0 = seg * 32;
        for (int c = c0; c < c0 + 32; ++c) {
            float v = BT[c * 66 + col];
            s += v; s2 += v * v;
        }
        red[col * 8 + seg] = s; red2[col * 8 + seg] = s2;
    }
    __syncthreads();
    if (threadIdx.x < 66) {
        int col = threadIdx.x;
        float s = 0.f, s2 = 0.f;
        for (int k = 0; k < 8; k++) { s += red[col * 8 + k]; s2 += red2[col * 8 + k]; }
        float m = s * (1.0f / 256.0f);
        float v = s2 * (1.0f / 256.0f) - m * m;
        mm[col] = m;
        iv[col] = 1.0f / sqrtf(v + 1e-5f);
    }
    __syncthreads();
    for (int i = threadIdx.x; i < 256 * 66; i += 512) {
        int c = i / 66, j = i - c * 66;
        int t = t0 - 2 + j;
        float val = 0.f;
        if (t >= 0) val = (BT[i] - mm[j]) * iv[j] * lng[c] + lnb[c];
        BT[i] = val;  // causal zero-pad for t<0
    }
    __syncthreads();

    const int tl = threadIdx.x & 63;
    const int g = __builtin_amdgcn_readfirstlane((int)(threadIdx.x >> 6));
    const float kscale = 0.5773502691896258f;  // 3^-0.5
    const size_t goff = (size_t)b * 512 * T;

    for (int p = 0; p < 2; ++p) {  // BT read-only: no barrier needed
        float acc[32];
#pragma unroll
        for (int o = 0; o < 32; o++) acc[o] = 0.f;
        const float* w1p = w1t + (p * 256 + g * 32);  // wave-uniform offset
        for (int c = 0; c < 256; ++c) {
#pragma unroll
            for (int k = 0; k < 3; ++k) {
                float xv = BT[c * 66 + tl + k];
                const float* wr = w1p + (size_t)(c * 3 + k) * 512;
#pragma unroll
                for (int o = 0; o < 32; o++) acc[o] = fmaf(wr[o], xv, acc[o]);
            }
        }
#pragma unroll
        for (int o = 0; o < 32; o++) {
            int oc = p * 256 + g * 32 + o;
            float y = (acc[o] + b1[oc]) * kscale;
            float ge = 0.5f * y * (1.0f + erff(y * 0.7071067811865476f));
            gout[goff + (size_t)oc * T + t0 + tl] = ge;
        }
    }
}

// ---------------- sub-block part 2: 1x1 conv(512->256) + residual + mask ----
// xout = (xin + W2*gin + b2) * mask.  LDS 32 KB chunk staging.
__global__ __launch_bounds__(512, 4) void k_conv2(
    const float* __restrict__ gin,   // [b][512][T]
    const float* __restrict__ xin, float* __restrict__ xout,
    const float* __restrict__ w2t,   // [512][256]
    const float* __restrict__ b2,
    const float* __restrict__ mask, int T) {
    __shared__ float S[128 * 64];    // 32 KB
    const int b = blockIdx.y, t0 = blockIdx.x * 64;
    const int tl = threadIdx.x & 63;
    const int g = __builtin_amdgcn_readfirstlane((int)(threadIdx.x >> 6));
    const size_t goff = (size_t)b * 512 * T;

    float acc[32];
#pragma unroll
    for (int o = 0; o < 32; o++) acc[o] = 0.f;

    for (int ch = 0; ch < 4; ch++) {
        __syncthreads();  // protect S from previous chunk's readers
        float4* S4 = (float4*)S;
        for (int i = threadIdx.x; i < 2048; i += 512) {  // 128 rows x 16 f4
            int r = i >> 4, cq = i & 15;
            S4[i] = *(const float4*)&gin[goff + (size_t)(ch * 128 + r) * T +
                                         t0 + cq * 4];
        }
        __syncthreads();
        const float* w2p = w2t + (size_t)(ch * 128) * 256 + g * 32;
        for (int r = 0; r < 128; ++r) {
            float xv = S[r * 64 + tl];
            const float* wr = w2p + (size_t)r * 256;
#pragma unroll
            for (int o = 0; o < 32; o++) acc[o] = fmaf(wr[o], xv, acc[o]);
        }
    }
    const size_t xoff = (size_t)b * 256 * T;
    float mk = mask[(size_t)b * T + t0 + tl];
#pragma unroll
    for (int o = 0; o < 32; o++) {
        int oc = g * 32 + o;
        size_t adr = xoff + (size_t)oc * T + t0 + tl;
        xout[adr] = (xin[adr] + acc[o] + b2[oc]) * mk;
    }
}

// ---------------- final LN + causal conv (k=3, 256->256) --------------------
__global__ __launch_bounds__(512) void k_lnconv(
    const float* __restrict__ xin, float* __restrict__ xout,
    const float* __restrict__ lg, const float* __restrict__ lb,
    const float* __restrict__ wt, const float* __restrict__ bias,
    const float* __restrict__ mask, int T) {
    extern __shared__ float sm[];
    float* BT = sm;             // 256*66
    float* red = sm + 256 * 66; // 528
    float* red2 = red + 528;    // 528
    float* mm = red2 + 528;     // 66
    float* iv = mm + 66;        // 66

    const int b = blockIdx.y;
    const int t0 = blockIdx.x * 64;
    const size_t xoff = (size_t)b * 256 * T;

    for (int i = threadIdx.x; i < 256 * 66; i += 512) {
        int c = i / 66, j = i - c * 66;
        int t = t0 - 2 + j;
        BT[i] = (t >= 0) ? xin[xoff + (size_t)c * T + t] : 0.0f;
    }
    __syncthreads();
    for (int i = threadIdx.x; i < 528; i += 512) {
        int col = i % 66, seg = i / 66;
        float s = 0.f, s2 = 0.f;
        int c0 = seg * 32;
        for (int c = c0; c < c0 + 32; ++c) {
            float v = BT[c * 66 + col];
            s += v; s2 += v * v;
        }
        red[col * 8 + seg] = s; red2[col * 8 + seg] = s2;
    }
    __syncthreads();
    if (threadIdx.x < 66) {
        int col = threadIdx.x;
        float s = 0.f, s2 = 0.f;
        for (int k = 0; k < 8; k++) { s += red[col * 8 + k]; s2 += red2[col * 8 + k]; }
        float m = s * (1.0f / 256.0f);
        float v = s2 * (1.0f / 256.0f) - m * m;
        mm[col] = m;
        iv[col] = 1.0f / sqrtf(v + 1e-5f);
    }
    __syncthreads();
    for (int i = threadIdx.x; i < 256 * 66; i += 512) {
        int c = i / 66, j = i - c * 66;
        int t = t0 - 2 + j;
        float val = 0.f;
        if (t >= 0)
            val = ((BT[i] - mm[j]) * iv[j] * lg[c] + lb[c]) * mask[(size_t)b * T + t];
        BT[i] = val;
    }
    __syncthreads();
    const int tl = threadIdx.x & 63;
    const int g = __builtin_amdgcn_readfirstlane((int)(threadIdx.x >> 6));
    float acc[32];
#pragma unroll
    for (int o = 0; o < 32; o++) acc[o] = 0.f;
    const float* wp = wt + g * 32;
    for (int c = 0; c < 256; ++c) {
#pragma unroll
        for (int k = 0; k < 3; ++k) {
            float xv = BT[c * 66 + tl + k];
            const float* wr = wp + (size_t)(c * 3 + k) * 256;
#pragma unroll
            for (int o = 0; o < 32; o++) acc[o] = fmaf(wr[o], xv, acc[o]);
        }
    }
    float mk = mask[(size_t)b * T + t0 + tl];
#pragma unroll
    for (int o = 0; o < 32; o++) {
        int oc = g * 32 + o;
        xout[xoff + (size_t)oc * T + t0 + tl] = (acc[o] + bias[oc]) * mk;
    }
}

// ---------------- group-by-segments (scatter mean) --------------------------
__global__ __launch_bounds__(256) void k_counts(const int* __restrict__ m2p,
                                                int* __restrict__ cnt) {
    __shared__ int c[512];
    int b = blockIdx.x;
    for (int i = threadIdx.x; i < 512; i += 256) c[i] = 0;
    __syncthreads();
    for (int t = threadIdx.x; t < 2048; t += 256) {
        int p = m2p[b * 2048 + t];
        if (p >= 1 && p <= 512) atomicAdd(&c[p - 1], 1);
    }
    __syncthreads();
    for (int i = threadIdx.x; i < 512; i += 256) cnt[b * 512 + i] = c[i];
}

__global__ __launch_bounds__(256) void k_scatter(const float* __restrict__ h,
                                                 const int* __restrict__ m2p,
                                                 float* __restrict__ g) {
    extern __shared__ float sm[];
    float* HT = sm;                    // 256*65 (padded)
    int* ph = (int*)(sm + 256 * 65);   // 64
    int b = blockIdx.y, t0 = blockIdx.x * 64;
    if (threadIdx.x < 64) ph[threadIdx.x] = m2p[b * 2048 + t0 + threadIdx.x];
    for (int i = threadIdx.x; i < 256 * 64; i += 256) {
        int c = i >> 6, j = i & 63;
        HT[c * 65 + j] = h[((size_t)b * 256 + c) * 2048 + t0 + j];
    }
    __syncthreads();
    int c = threadIdx.x;
    float run = 0.f;
    int cur = ph[0];
    for (int j = 0; j < 64; j++) {
        int p = ph[j];
        if (p != cur) {
            if (cur >= 1 && cur <= 512)
                atomicAdd(&g[((size_t)b * 256 + c) * 512 + cur - 1], run);
            run = 0.f;
            cur = p;
        }
        run += HT[c * 65 + j];
    }
    if (cur >= 1 && cur <= 512)
        atomicAdd(&g[((size_t)b * 256 + c) * 512 + cur - 1], run);
}

__global__ __launch_bounds__(256) void k_divide(float* __restrict__ g,
                                                const int* __restrict__ cnt) {
    int n = blockIdx.x * 256 + threadIdx.x;
    if (n >= 16 * 256 * 512) return;
    int l = n & 511;
    int b = n >> 17;
    int c1 = cnt[b * 512 + l];
    if (c1 < 1) c1 = 1;
    g[n] = g[n] / (float)c1;
}

// ---------------- VQ --------------------------------------------------------
__global__ __launch_bounds__(256) void k_vq(const float* __restrict__ z,
                                            const float* __restrict__ cb,
                                            int* __restrict__ idxout,
                                            float* __restrict__ out,
                                            float* __restrict__ lossacc) {
    int n = blockIdx.x * 256 + threadIdx.x;  // 0..8191
    int b = n >> 9, l = n & 511;
    float zr[64];
#pragma unroll
    for (int c = 0; c < 64; c++) zr[c] = z[((size_t)b * 64 + c) * 512 + l];
    float best = 3.4e38f;
    int bi = 0;
    for (int k = 0; k < 128; k++) {
        const float* cr = cb + k * 64;  // uniform -> s_load
        float d = 0.f;
#pragma unroll
        for (int c = 0; c < 64; c++) {
            float t = zr[c] - cr[c];
            d = fmaf(t, t, d);
        }
        if (d < best) { best = d; bi = k; }  // strict < == np first-argmin
    }
    idxout[n] = bi;
    out[OUT_IDX_OFF + n] = (float)bi;
    atomicAdd(lossacc, best);
}

__global__ void k_loss(const float* __restrict__ acc,
                       float* __restrict__ out) {
    if (threadIdx.x == 0 && blockIdx.x == 0)
        out[OUT_LOSS_OFF] = 0.25f * acc[0] * (1.0f / 524288.0f);
}

// ---------------- proj_out (q = codebook[idx]) ------------------------------
__global__ __launch_bounds__(256) void k_projout(const float* __restrict__ cb,
                                                 const int* __restrict__ idx,
                                                 const float* __restrict__ wt,
                                                 const float* __restrict__ bias,
                                                 float* __restrict__ out) {
    __shared__ float Q[64 * 64];  // [c][l]
    __shared__ int ids[64];
    int b = blockIdx.y, l0 = blockIdx.x * 64;
    if (threadIdx.x < 64) ids[threadIdx.x] = idx[b * 512 + l0 + threadIdx.x];
    __syncthreads();
    for (int i = threadIdx.x; i < 4096; i += 256) {
        int c = i >> 6, l = i & 63;
        Q[c * 64 + l] = cb[ids[l] * 64 + c];
    }
    __syncthreads();
    int tl = threadIdx.x & 63;
    int g = __builtin_amdgcn_readfirstlane((int)(threadIdx.x >> 6));
    float acc[64];
#pragma unroll
    for (int o = 0; o < 64; o++) acc[o] = 0.f;
    for (int i = 0; i < 64; i++) {
        float xv = Q[i * 64 + tl];
        const float* wr = wt + i * 256 + g * 64;
#pragma unroll
        for (int o = 0; o < 64; o++) acc[o] = fmaf(wr[o], xv, acc[o]);
    }
#pragma unroll
    for (int o = 0; o < 64; o++) {
        int oc = g * 64 + o;
        out[(size_t)b * 131072 + (size_t)oc * 512 + l0 + tl] = acc[o] + bias[oc];
    }
}

// ---------------------------------------------------------------------------
extern "C" void kernel_launch(void* const* d_in, const int* in_sizes, int n_in,
                              void* d_out, int out_size, void* d_ws, size_t ws_size,
                              hipStream_t stream) {
    (void)in_sizes; (void)n_in; (void)out_size; (void)ws_size;
    const float* x          = (const float*)d_in[0];
    const float* in_np      = (const float*)d_in[1];
    const int*   mel2ph     = (const int*)d_in[2];
    const float* ph_np      = (const float*)d_in[3];
    const float* conv_in_w  = (const float*)d_in[4];
    const float* conv_in_b  = (const float*)d_in[5];
    const float* e_ln_g = (const float*)d_in[6];
    const float* e_ln_b = (const float*)d_in[7];
    const float* e_w1   = (const float*)d_in[8];
    const float* e_b1   = (const float*)d_in[9];
    const float* e_w2   = (const float*)d_in[10];
    const float* e_b2   = (const float*)d_in[11];
    const float* e_lg   = (const float*)d_in[12];
    const float* e_lb   = (const float*)d_in[13];
    const float* e_pw   = (const float*)d_in[14];
    const float* e_pb   = (const float*)d_in[15];
    const float* p_ln_g = (const float*)d_in[16];
    const float* p_ln_b = (const float*)d_in[17];
    const float* p_w1   = (const float*)d_in[18];
    const float* p_b1   = (const float*)d_in[19];
    const float* p_w2   = (const float*)d_in[20];
    const float* p_b2   = (const float*)d_in[21];
    const float* p_lg   = (const float*)d_in[22];
    const float* p_lb   = (const float*)d_in[23];
    const float* p_pw   = (const float*)d_in[24];
    const float* p_pb   = (const float*)d_in[25];
    const float* proj_in_w  = (const float*)d_in[26];
    const float* proj_in_b  = (const float*)d_in[27];
    const float* proj_out_w = (const float*)d_in[28];
    const float* proj_out_b = (const float*)d_in[29];
    const float* codebook   = (const float*)d_in[30];
    float* out = (float*)d_out;

    float* ws = (float*)d_ws;
    float* A      = ws;                        // 16*256*2048 = 8388608
    float* Bb     = A + 8388608;               // 8388608
    float* W1T_E  = Bb + 8388608;              // 10*768*512 = 3932160
    float* W1T_P  = W1T_E + 3932160;
    float* W2T_E  = W1T_P + 3932160;           // 10*512*256 = 1310720
    float* W2T_P  = W2T_E + 1310720;
    float* CINT   = W2T_P + 1310720;           // 80*256
    float* PSTT_E = CINT + 20480;              // 768*256
    float* PSTT_P = PSTT_E + 196608;
    float* PINT   = PSTT_P + 196608;           // 256*64
    float* POUTT  = PINT + 16384;              // 64*256
    float* Z      = POUTT + 16384;             // 16*64*512 = 524288
    int*   CNT    = (int*)(Z + 524288);        // 8192
    int*   IDX    = CNT + 8192;                // 8192
    float* LOSS   = (float*)(IDX + 8192);      // 1
    float* CTG    = LOSS + 1;                  // 16*512*2048 = 16777216 (64 MB)

    // weight transposes (d_ws is re-poisoned every call -> recompute)
    k_t_conv3<<<dim3(2048), dim3(256), 0, stream>>>(e_w1, W1T_E, 10, 512, 256);
    k_t_conv3<<<dim3(2048), dim3(256), 0, stream>>>(p_w1, W1T_P, 10, 512, 256);
    k_t_mat  <<<dim3(1024), dim3(256), 0, stream>>>(e_w2, W2T_E, 10, 256, 512);
    k_t_mat  <<<dim3(1024), dim3(256), 0, stream>>>(p_w2, W2T_P, 10, 256, 512);
    k_t_mat  <<<dim3(80),   dim3(256), 0, stream>>>(conv_in_w, CINT, 1, 256, 80);
    k_t_conv3<<<dim3(768),  dim3(256), 0, stream>>>(e_pw, PSTT_E, 1, 256, 256);
    k_t_conv3<<<dim3(768),  dim3(256), 0, stream>>>(p_pw, PSTT_P, 1, 256, 256);
    k_t_mat  <<<dim3(64),   dim3(256), 0, stream>>>(proj_in_w, PINT, 1, 64, 256);
    k_t_mat  <<<dim3(64),   dim3(256), 0, stream>>>(proj_out_w, POUTT, 1, 256, 64);

    const size_t sm_c1  = (256 * 66 + 528 + 528 + 66 + 66) * sizeof(float);  // 72 KB
    const size_t sm_lnc = sm_c1;
    const size_t sm_scat = 256 * 65 * sizeof(float) + 64 * sizeof(int);

    // ---- conv_in + mask -> A
    k_pw<80, 256, 64><<<dim3(32, 16), dim3(256), 80 * 64 * 4, stream>>>(
        x, CINT, conv_in_b, in_np, A, 2048);

    // ---- encoder: 10 sub-blocks, ping-pong A<->B (ends in A)
    float* cur = A;
    float* nxt = Bb;
    for (int s = 0; s < 10; s++) {
        k_conv1<<<dim3(32, 16), dim3(512), sm_c1, stream>>>(
            cur, CTG, e_ln_g + s * 256, e_ln_b + s * 256,
            W1T_E + (size_t)s * 768 * 512, e_b1 + s * 512, 2048);
        k_conv2<<<dim3(32, 16), dim3(512), 0, stream>>>(
            CTG, cur, nxt, W2T_E + (size_t)s * 512 * 256, e_b2 + s * 256,
            in_np, 2048);
        float* t = cur; cur = nxt; nxt = t;
    }
    // ---- final LN + post conv: A -> B
    k_lnconv<<<dim3(32, 16), dim3(512), sm_lnc, stream>>>(
        cur, nxt, e_lg, e_lb, PSTT_E, e_pb, in_np, 2048);

    // ---- group-by-segs: B (T=2048) -> A (compact [16,256,512])
    hipMemsetAsync(A, 0, (size_t)2097152 * 4, stream);
    hipMemsetAsync(LOSS, 0, 4, stream);
    k_counts<<<dim3(16), dim3(256), 0, stream>>>(mel2ph, CNT);
    k_scatter<<<dim3(32, 16), dim3(256), sm_scat, stream>>>(Bb, mel2ph, A);
    k_divide<<<dim3(8192), dim3(256), 0, stream>>>(A, CNT);

    // ---- postnet: 10 sub-blocks on T=512, ping-pong (ends in A)
    cur = A; nxt = Bb;
    for (int s = 0; s < 10; s++) {
        k_conv1<<<dim3(8, 16), dim3(512), sm_c1, stream>>>(
            cur, CTG, p_ln_g + s * 256, p_ln_b + s * 256,
            W1T_P + (size_t)s * 768 * 512, p_b1 + s * 512, 512);
        k_conv2<<<dim3(8, 16), dim3(512), 0, stream>>>(
            CTG, cur, nxt, W2T_P + (size_t)s * 512 * 256, p_b2 + s * 256,
            ph_np, 512);
        float* t = cur; cur = nxt; nxt = t;
    }
    k_lnconv<<<dim3(8, 16), dim3(512), sm_lnc, stream>>>(
        cur, nxt, p_lg, p_lb, PSTT_P, p_pb, ph_np, 512);

    // ---- proj_in: B -> Z [16,64,512]
    k_pw<256, 64, 16><<<dim3(8, 16), dim3(256), 256 * 64 * 4, stream>>>(
        Bb, PINT, proj_in_b, nullptr, Z, 512);

    // ---- VQ + loss + proj_out
    k_vq<<<dim3(32), dim3(256), 0, stream>>>(Z, codebook, IDX, out, LOSS);
    k_loss<<<dim3(1), dim3(64), 0, stream>>>(LOSS, out);
    k_projout<<<dim3(8, 16), dim3(256), 0, stream>>>(codebook, IDX, POUTT,
                                                     proj_out_b, out);
}